// Round 9
// baseline (323.342 us; speedup 1.0000x reference)
//
#include <hip/hip_runtime.h>
#include <stdint.h>
#include <stddef.h>

// ThresholdMoE: out = sum_e w[n,e] * (x @ A_e) @ B_e, w = renorm(softmax(x@gw+b) >= 0.1)
// N=65536 tokens, D=1024, E=8, R=64, ER=512.
// R9: fused kernel tuned: (1) X tile in A-frag-packed LDS layout (conflict-free
//     af reads), (2) phase-2 bv register double-buffer (L2 latency hidden under
//     MFMA), (3) C-stores reordered m->r->n for write-combining.

typedef float f32x4 __attribute__((ext_vector_type(4)));
typedef short bf16x8 __attribute__((ext_vector_type(8)));

#define MFMA_16x16x32(A, B, C) __builtin_amdgcn_mfma_f32_16x16x32_bf16((A), (B), (C), 0, 0, 0)
#define SCHED_FENCE() __builtin_amdgcn_sched_barrier(0)
#define BAR() __builtin_amdgcn_s_barrier()
#define WAIT_LGKM0() asm volatile("s_waitcnt lgkmcnt(0)" ::: "memory")
#define WAIT_VM0_LGKM0() asm volatile("s_waitcnt vmcnt(0) lgkmcnt(0)" ::: "memory")

__device__ __forceinline__ unsigned short f2bf(float f) {
    union { float f; unsigned int u; } v;
    v.f = f;
    unsigned int u = v.u;
    u += 0x7FFFu + ((u >> 16) & 1u);   // RNE
    return (unsigned short)(u >> 16);
}

__device__ __forceinline__ void load16_lds(unsigned short* lds, const unsigned short* g) {
    __builtin_amdgcn_global_load_lds(
        (const __attribute__((address_space(1))) unsigned int*)g,
        (__attribute__((address_space(3))) unsigned int*)lds, 16, 0, 0);
}

// ---------------------------------------------------------------------------
// Pack lora_A / lora_B to bf16 in MFMA B-fragment order.
// A_P: [D/32=32][ER/16=32][lane 64][j 8], element = A_cat[d][e*64+r]
// B_P: [ER/32=16][D/16=64][lane 64][j 8], element = B_cat[e*64+r][d]
// ---------------------------------------------------------------------------
__global__ __launch_bounds__(256) void convert_pack(
        const float* __restrict__ LA, const float* __restrict__ LB,
        unsigned short* __restrict__ A_P, unsigned short* __restrict__ B_P) {
    int gid = blockIdx.x * 256 + threadIdx.x;          // 0 .. 1048575
    if (gid < 524288) {
        int j = gid & 7, l = (gid >> 3) & 63, cblk = (gid >> 9) & 31, kblk = gid >> 14;
        int d = kblk * 32 + (l >> 4) * 8 + j;
        int col = cblk * 16 + (l & 15);
        int e = col >> 6, r = col & 63;
        A_P[gid] = f2bf(LA[((size_t)e * 1024 + d) * 64 + r]);   // lora_A[e][d][r]
    } else {
        int idx = gid - 524288;
        int j = idx & 7, l = (idx >> 3) & 63, cblk = (idx >> 9) & 63, kblk = idx >> 15;
        int k = kblk * 32 + (l >> 4) * 8 + j;          // index into ER
        int d = cblk * 16 + (l & 15);
        int e = k >> 6, r = k & 63;
        B_P[idx] = f2bf(LB[((size_t)e * 64 + r) * 1024 + d]);   // lora_B[e][r][d]
    }
}

// ---------------------------------------------------------------------------
// Gate: fp32, exact. 16 threads/token. GW transposed in LDS; all 16 X loads
// issued upfront (validated R8: ~2x faster than demand-loading).
// ---------------------------------------------------------------------------
__global__ __launch_bounds__(256) void gate_kernel(
        const float* __restrict__ X, const float* __restrict__ GW,
        const float* __restrict__ GB, float* __restrict__ Wg) {
    __shared__ float gwt[8 * 1024];   // 32KB: GW_T[e][k]
    int tid = threadIdx.x;

    {   // stage GW transposed: thread t loads GW rows [t*4, t*4+4)
        float r[4][8];
#pragma unroll
        for (int j = 0; j < 4; ++j) {
            const f32x4* gp = (const f32x4*)(GW + (size_t)(tid * 4 + j) * 8);
            f32x4 g0 = gp[0], g1 = gp[1];
#pragma unroll
            for (int q = 0; q < 4; ++q) { r[j][q] = g0[q]; r[j][4 + q] = g1[q]; }
        }
#pragma unroll
        for (int e = 0; e < 8; ++e) {
            f32x4 v;
#pragma unroll
            for (int j = 0; j < 4; ++j) v[j] = r[j][e];
            *(f32x4*)&gwt[e * 1024 + tid * 4] = v;
        }
    }
    __syncthreads();

    int row = blockIdx.x * 16 + (tid >> 4);
    int sub = tid & 15;
    const float* xr = X + (size_t)row * 1024 + sub * 4;

    f32x4 xs[16];
#pragma unroll
    for (int it = 0; it < 16; ++it) xs[it] = *(const f32x4*)(xr + it * 64);

    float lg[8];
#pragma unroll
    for (int e = 0; e < 8; ++e) lg[e] = 0.f;

#pragma unroll
    for (int it = 0; it < 16; ++it) {
        f32x4 g[8];
#pragma unroll
        for (int e = 0; e < 8; ++e)
            g[e] = *(const f32x4*)&gwt[e * 1024 + it * 64 + sub * 4];
        f32x4 x = xs[it];
#pragma unroll
        for (int e = 0; e < 8; ++e) {
            lg[e] += x[0] * g[e][0];
            lg[e] += x[1] * g[e][1];
            lg[e] += x[2] * g[e][2];
            lg[e] += x[3] * g[e][3];
        }
    }
#pragma unroll
    for (int s = 1; s < 16; s <<= 1) {
#pragma unroll
        for (int e = 0; e < 8; ++e) lg[e] += __shfl_xor(lg[e], s, 16);
    }
    float p[8], m = -1e30f, ssum = 0.f;
#pragma unroll
    for (int e = 0; e < 8; ++e) { lg[e] += GB[e]; m = fmaxf(m, lg[e]); }
#pragma unroll
    for (int e = 0; e < 8; ++e) { p[e] = expf(lg[e] - m); ssum += p[e]; }
    float inv = 1.f / ssum;
    float wv[8], wsum = 0.f;
#pragma unroll
    for (int e = 0; e < 8; ++e) {
        float pe = p[e] * inv;
        wv[e] = (pe >= 0.1f) ? pe : 0.f;
        wsum += wv[e];
    }
    if (wsum == 0.f) wsum = 1.f;
    float invw = 1.f / wsum;
    if (sub < 8) Wg[(size_t)row * 8 + sub] = wv[sub] * invw;
}

// ---------------------------------------------------------------------------
// Fused stages: per 64-token block, 8 waves.
// Phase 1: H = w * (x @ A_cat) -> LDS hb[64][520]. X tile stored in A-frag
//   packed layout x[m 4][lane 64][j 8] => af reads are consecutive b128
//   (conflict-free). A double-buffered via global_load_lds.
// Phase 2: out = hb @ B_cat; bv (B-frags) register double-buffered from
//   L2-resident B_P; af2 from hb (stride 520 = 2-way = free). C-stores in
//   m->r->n order (256B contiguous runs per row).
// ---------------------------------------------------------------------------
__global__ __launch_bounds__(512, 4) void fused_kernel(
        const float* __restrict__ X, const unsigned short* __restrict__ A_P,
        const unsigned short* __restrict__ B_P, const float* __restrict__ Wg,
        float* __restrict__ Out) {
    __shared__ union SM1 {
        struct {
            unsigned short a[2][32 * 512];   // 2 x 32KB packed-A tiles
            unsigned short x[2][2048];       // 2 x 4KB X frag tiles [4][64][8]
        } p;
        unsigned short hb[64 * 520];         // H tile [64][512+8 pad], 66560B
    } sm;
    __shared__ float wl[512];                // weights [64 tok][8 e]

    int tid = threadIdx.x;
    int lane = tid & 63;
    int w = tid >> 6;                        // wave 0..7 == expert id (phase 1)
    int blk = blockIdx.x;
    int row = tid >> 3;                      // 0..63 (X staging row)
    int sub = tid & 7;

    wl[tid] = Wg[(size_t)blk * 512 + tid];

    const float* xp = X + (size_t)blk * 64 * 1024 + (size_t)row * 1024 + sub * 4;
    // frag-packed x write offset (kb-invariant): elem (row, k=sub*4..+3) ->
    // x[row>>4][(row&15)|((sub>>1)<<4)][(sub&1)*4]
    int xw_off = (row >> 4) * 512 + (((row & 15) | ((sub >> 1) << 4)) * 8) + (sub & 1) * 4;

    unsigned short* aCur = sm.p.a[0];
    unsigned short* aNxt = sm.p.a[1];
    unsigned short* xCur = sm.p.x[0];
    unsigned short* xNxt = sm.p.x[1];

    // ---- phase 1 prologue ----
    {
        const unsigned short* asrc = A_P + tid * 8;
#pragma unroll
        for (int i = 0; i < 4; ++i)
            load16_lds(&aCur[tid * 8 + i * 4096], asrc + i * 4096);
    }
    SCHED_FENCE();
    f32x4 xv0 = *(const f32x4*)(xp);
    f32x4 xv_hold = *(const f32x4*)(xp + 32);
    {   // write x(0); implicit wait for xv0 also drains GLL A(0)
        unsigned int lo = (unsigned int)f2bf(xv0[0]) | ((unsigned int)f2bf(xv0[1]) << 16);
        unsigned int hi = (unsigned int)f2bf(xv0[2]) | ((unsigned int)f2bf(xv0[3]) << 16);
        *((uint2*)&xCur[xw_off]) = make_uint2(lo, hi);
    }

    f32x4 acc[4][4] = {};
    for (int kb = 0; kb < 31; ++kb) {
        const unsigned short* asrc = A_P + (size_t)(kb + 1) * 16384 + tid * 8;
#pragma unroll
        for (int i = 0; i < 4; ++i)
            load16_lds(&aNxt[tid * 8 + i * 4096], asrc + i * 4096);
        SCHED_FENCE();
        int kbn = (kb + 2 <= 31) ? kb + 2 : 31;
        f32x4 xv_new = *(const f32x4*)(xp + (size_t)kbn * 32);
        // write x(kb+1); implicit vmcnt wait on xv_hold drains GLL A(kb)
        unsigned int lo = (unsigned int)f2bf(xv_hold[0]) | ((unsigned int)f2bf(xv_hold[1]) << 16);
        unsigned int hi = (unsigned int)f2bf(xv_hold[2]) | ((unsigned int)f2bf(xv_hold[3]) << 16);
        *((uint2*)&xNxt[xw_off]) = make_uint2(lo, hi);
        WAIT_LGKM0();
        SCHED_FENCE();
        BAR();
        SCHED_FENCE();
        bf16x8 af[4], bv[4];
#pragma unroll
        for (int m = 0; m < 4; ++m)
            af[m] = *(const bf16x8*)&xCur[m * 512 + lane * 8];
#pragma unroll
        for (int n = 0; n < 4; ++n)
            bv[n] = *(const bf16x8*)&aCur[(w * 4 + n) * 512 + lane * 8];
#pragma unroll
        for (int m = 0; m < 4; ++m)
#pragma unroll
            for (int n = 0; n < 4; ++n)
                acc[m][n] = MFMA_16x16x32(af[m], bv[n], acc[m][n]);
        BAR();
        unsigned short* t;
        t = aCur; aCur = aNxt; aNxt = t;
        t = xCur; xCur = xNxt; xNxt = t;
        xv_hold = xv_new;
    }
    // peeled kb=31
    WAIT_VM0_LGKM0();
    SCHED_FENCE();
    BAR();
    SCHED_FENCE();
    {
        bf16x8 af[4], bv[4];
#pragma unroll
        for (int m = 0; m < 4; ++m)
            af[m] = *(const bf16x8*)&xCur[m * 512 + lane * 8];
#pragma unroll
        for (int n = 0; n < 4; ++n)
            bv[n] = *(const bf16x8*)&aCur[(w * 4 + n) * 512 + lane * 8];
#pragma unroll
        for (int m = 0; m < 4; ++m)
#pragma unroll
            for (int n = 0; n < 4; ++n)
                acc[m][n] = MFMA_16x16x32(af[m], bv[n], acc[m][n]);
    }
    __syncthreads();   // staging dead; hb (union) becomes live

    // phase 1 epilogue: scale by weight, bf16 -> hb[64][520]
#pragma unroll
    for (int m = 0; m < 4; ++m) {
        float wv[4];
#pragma unroll
        for (int r = 0; r < 4; ++r)
            wv[r] = wl[(m * 16 + (lane >> 4) * 4 + r) * 8 + w];
#pragma unroll
        for (int n = 0; n < 4; ++n) {
            int col = w * 64 + n * 16 + (lane & 15);
#pragma unroll
            for (int r = 0; r < 4; ++r) {
                int rr = m * 16 + (lane >> 4) * 4 + r;
                sm.hb[rr * 520 + col] = f2bf(acc[m][n][r] * wv[r]);
            }
        }
    }
    __syncthreads();

    // ---- phase 2: out = hb @ B_cat (wave w owns cols w*128..+127) ----
#pragma unroll
    for (int h = 0; h < 2; ++h) {
        f32x4 acc2[4][4] = {};
        int cb0 = w * 8 + h * 4;             // cblk base (16-col blocks)
        bf16x8 bvC[4], bvN[4];
#pragma unroll
        for (int n = 0; n < 4; ++n)
            bvC[n] = *(const bf16x8*)(B_P + (((size_t)cb0 + n) * 64 + lane) * 8);
        for (int kc = 0; kc < 16; ++kc) {
            bf16x8 af2[4];
#pragma unroll
            for (int m = 0; m < 4; ++m)
                af2[m] = *(const bf16x8*)&sm.hb[(m * 16 + (lane & 15)) * 520 + kc * 32 + (lane >> 4) * 8];
            if (kc < 15) {
#pragma unroll
                for (int n = 0; n < 4; ++n)
                    bvN[n] = *(const bf16x8*)(B_P + (((size_t)(kc + 1) * 64 + cb0 + n) * 64 + lane) * 8);
            }
#pragma unroll
            for (int m = 0; m < 4; ++m)
#pragma unroll
                for (int n = 0; n < 4; ++n)
                    acc2[m][n] = MFMA_16x16x32(af2[m], bvC[n], acc2[m][n]);
            if (kc < 15) {
#pragma unroll
                for (int n = 0; n < 4; ++n) bvC[n] = bvN[n];
            }
        }
        size_t rb = (size_t)blk * 64;
        int cb = w * 128 + h * 64;
#pragma unroll
        for (int m = 0; m < 4; ++m)
#pragma unroll
            for (int r = 0; r < 4; ++r) {
                size_t rrow = rb + m * 16 + (lane >> 4) * 4 + r;
                float* orow = Out + rrow * 1024 + cb + (lane & 15);
#pragma unroll
                for (int n = 0; n < 4; ++n)
                    orow[n * 16] = acc2[m][n][r];
            }
    }
}

// ---------------------------------------------------------------------------
extern "C" void kernel_launch(void* const* d_in, const int* in_sizes, int n_in,
                              void* d_out, int out_size, void* d_ws, size_t ws_size,
                              hipStream_t stream) {
    const float* X  = (const float*)d_in[0];   // [65536][1024]
    const float* GW = (const float*)d_in[1];   // [1024][8]
    const float* GB = (const float*)d_in[2];   // [8]
    const float* LA = (const float*)d_in[3];   // [8][1024][64]
    const float* LB = (const float*)d_in[4];   // [8][64][1024]
    float* Out = (float*)d_out;                // [65536][1024]

    char* ws = (char*)d_ws;
    float*          Wg  = (float*)ws;                              // 2MB  [N][8]
    unsigned short* A_P = (unsigned short*)(ws + (2u << 20));      // 1MB  packed lora_A
    unsigned short* B_P = (unsigned short*)(ws + (3u << 20));      // 1MB  packed lora_B

    convert_pack<<<4096, 256, 0, stream>>>(LA, LB, A_P, B_P);
    gate_kernel<<<4096, 256, 0, stream>>>(X, GW, GB, Wg);
    fused_kernel<<<1024, 512, 0, stream>>>(X, A_P, B_P, Wg, Out);
}

// Round 10
// 281.297 us; speedup vs baseline: 1.1495x; 1.1495x over previous
//
#include <hip/hip_runtime.h>
#include <stdint.h>
#include <stddef.h>

// ThresholdMoE: out = sum_e w[n,e] * (x @ A_e) @ B_e, w = renorm(softmax(x@gw+b) >= 0.1)
// N=65536 tokens, D=1024, E=8, R=64, ER=512.
// R10: consolidation — best measured components only.
//   pack (R1)  + gate (R8 upfront-16-load, ~55us) +
//   stage1 (R4 pipeline, ~105us) + stage2 (R4 dbuf vmcnt(3), ~80us).
//   Fusion (R8/R9) measured SLOWER than split => reverted.

typedef float f32x4 __attribute__((ext_vector_type(4)));
typedef short bf16x8 __attribute__((ext_vector_type(8)));

#define MFMA_16x16x32(A, B, C) __builtin_amdgcn_mfma_f32_16x16x32_bf16((A), (B), (C), 0, 0, 0)
#define SCHED_FENCE() __builtin_amdgcn_sched_barrier(0)
#define BAR() __builtin_amdgcn_s_barrier()
#define WAIT_LGKM0() asm volatile("s_waitcnt lgkmcnt(0)" ::: "memory")
#define WAIT_VM3() asm volatile("s_waitcnt vmcnt(3)" ::: "memory")
#define WAIT_VM0_LGKM0() asm volatile("s_waitcnt vmcnt(0) lgkmcnt(0)" ::: "memory")
#define WAIT_VM0() asm volatile("s_waitcnt vmcnt(0)" ::: "memory")

__device__ __forceinline__ unsigned short f2bf(float f) {
    union { float f; unsigned int u; } v;
    v.f = f;
    unsigned int u = v.u;
    u += 0x7FFFu + ((u >> 16) & 1u);   // RNE
    return (unsigned short)(u >> 16);
}

__device__ __forceinline__ void load16_lds(unsigned short* lds, const unsigned short* g) {
    __builtin_amdgcn_global_load_lds(
        (const __attribute__((address_space(1))) unsigned int*)g,
        (__attribute__((address_space(3))) unsigned int*)lds, 16, 0, 0);
}

// ---------------------------------------------------------------------------
// Pack lora_A / lora_B to bf16 in MFMA B-fragment order.
// A_P: [D/32=32][ER/16=32][lane 64][j 8], element = A_cat[d][e*64+r]
// B_P: [ER/32=16][D/16=64][lane 64][j 8], element = B_cat[e*64+r][d]
// ---------------------------------------------------------------------------
__global__ __launch_bounds__(256) void convert_pack(
        const float* __restrict__ LA, const float* __restrict__ LB,
        unsigned short* __restrict__ A_P, unsigned short* __restrict__ B_P) {
    int gid = blockIdx.x * 256 + threadIdx.x;          // 0 .. 1048575
    if (gid < 524288) {
        int j = gid & 7, l = (gid >> 3) & 63, cblk = (gid >> 9) & 31, kblk = gid >> 14;
        int d = kblk * 32 + (l >> 4) * 8 + j;
        int col = cblk * 16 + (l & 15);
        int e = col >> 6, r = col & 63;
        A_P[gid] = f2bf(LA[((size_t)e * 1024 + d) * 64 + r]);   // lora_A[e][d][r]
    } else {
        int idx = gid - 524288;
        int j = idx & 7, l = (idx >> 3) & 63, cblk = (idx >> 9) & 63, kblk = idx >> 15;
        int k = kblk * 32 + (l >> 4) * 8 + j;          // index into ER
        int d = cblk * 16 + (l & 15);
        int e = k >> 6, r = k & 63;
        B_P[idx] = f2bf(LB[((size_t)e * 64 + r) * 1024 + d]);   // lora_B[e][r][d]
    }
}

// ---------------------------------------------------------------------------
// Gate: fp32, exact. 16 threads/token. GW transposed in LDS; all 16 X loads
// issued upfront (R8-validated: halves gate time vs demand loading).
// ---------------------------------------------------------------------------
__global__ __launch_bounds__(256) void gate_kernel(
        const float* __restrict__ X, const float* __restrict__ GW,
        const float* __restrict__ GB, float* __restrict__ Wg) {
    __shared__ float gwt[8 * 1024];   // 32KB: GW_T[e][k]
    int tid = threadIdx.x;

    {   // stage GW transposed: thread t loads GW rows [t*4, t*4+4)
        float r[4][8];
#pragma unroll
        for (int j = 0; j < 4; ++j) {
            const f32x4* gp = (const f32x4*)(GW + (size_t)(tid * 4 + j) * 8);
            f32x4 g0 = gp[0], g1 = gp[1];
#pragma unroll
            for (int q = 0; q < 4; ++q) { r[j][q] = g0[q]; r[j][4 + q] = g1[q]; }
        }
#pragma unroll
        for (int e = 0; e < 8; ++e) {
            f32x4 v;
#pragma unroll
            for (int j = 0; j < 4; ++j) v[j] = r[j][e];
            *(f32x4*)&gwt[e * 1024 + tid * 4] = v;
        }
    }
    __syncthreads();

    int row = blockIdx.x * 16 + (tid >> 4);
    int sub = tid & 15;
    const float* xr = X + (size_t)row * 1024 + sub * 4;

    f32x4 xs[16];
#pragma unroll
    for (int it = 0; it < 16; ++it) xs[it] = *(const f32x4*)(xr + it * 64);

    float lg[8];
#pragma unroll
    for (int e = 0; e < 8; ++e) lg[e] = 0.f;

#pragma unroll
    for (int it = 0; it < 16; ++it) {
        f32x4 g[8];
#pragma unroll
        for (int e = 0; e < 8; ++e)
            g[e] = *(const f32x4*)&gwt[e * 1024 + it * 64 + sub * 4];
        f32x4 x = xs[it];
#pragma unroll
        for (int e = 0; e < 8; ++e) {
            lg[e] += x[0] * g[e][0];
            lg[e] += x[1] * g[e][1];
            lg[e] += x[2] * g[e][2];
            lg[e] += x[3] * g[e][3];
        }
    }
#pragma unroll
    for (int s = 1; s < 16; s <<= 1) {
#pragma unroll
        for (int e = 0; e < 8; ++e) lg[e] += __shfl_xor(lg[e], s, 16);
    }
    float p[8], m = -1e30f, ssum = 0.f;
#pragma unroll
    for (int e = 0; e < 8; ++e) { lg[e] += GB[e]; m = fmaxf(m, lg[e]); }
#pragma unroll
    for (int e = 0; e < 8; ++e) { p[e] = expf(lg[e] - m); ssum += p[e]; }
    float inv = 1.f / ssum;
    float wv[8], wsum = 0.f;
#pragma unroll
    for (int e = 0; e < 8; ++e) {
        float pe = p[e] * inv;
        wv[e] = (pe >= 0.1f) ? pe : 0.f;
        wsum += wv[e];
    }
    if (wsum == 0.f) wsum = 1.f;
    float invw = 1.f / wsum;
    if (sub < 8) Wg[(size_t)row * 8 + sub] = wv[sub] * invw;
}

// ---------------------------------------------------------------------------
// Stage 1 (R4-validated): H[n, e*64+r] = w[n,e] * (x @ A_cat), bf16 out in
// stage2-A-frag packed order. 64 tokens/block, 8 waves, wave == expert.
// A double-buffered via global_load_lds, X double-prefetched in regs.
// ---------------------------------------------------------------------------
__global__ __launch_bounds__(512, 4) void stage1_kernel(
        const float* __restrict__ X, const unsigned short* __restrict__ A_P,
        const float* __restrict__ Wg, unsigned short* __restrict__ H_P) {
    __shared__ union SM1 {
        struct {
            unsigned short a[2][32 * 512];   // 2 x 32KB packed-A tiles
            unsigned short x[2][64 * 40];    // 2 x 5KB bf16 X tiles ([64][32+8pad])
        } p;
        unsigned short hb[64 * 520];         // H bounce [64][512+8 pad]
    } sm;
    __shared__ float wl[512];                // weights [64 tok][8 e]

    int tid = threadIdx.x;
    int lane = tid & 63;
    int w = tid >> 6;                        // wave 0..7 == expert id
    int blk = blockIdx.x;
    int row = tid >> 3;                      // 0..63 (X staging row)
    int sub = tid & 7;

    wl[tid] = Wg[(size_t)blk * 512 + tid];

    const float* xp = X + (size_t)blk * 64 * 1024 + (size_t)row * 1024 + sub * 4;
    unsigned short* aCur = sm.p.a[0];
    unsigned short* aNxt = sm.p.a[1];
    unsigned short* xCur = sm.p.x[0];
    unsigned short* xNxt = sm.p.x[1];

    // prologue: GLL A(0) first, then X(0), X(1) (order matters for vmcnt drain)
    {
        const unsigned short* asrc = A_P + tid * 8;
#pragma unroll
        for (int i = 0; i < 4; ++i)
            load16_lds(&aCur[tid * 8 + i * 4096], asrc + i * 4096);
    }
    SCHED_FENCE();
    f32x4 xv0 = *(const f32x4*)(xp);
    f32x4 xv_hold = *(const f32x4*)(xp + 32);
    {   // write x(0); implicit wait for xv0 also drains GLL A(0)
        unsigned int lo = (unsigned int)f2bf(xv0[0]) | ((unsigned int)f2bf(xv0[1]) << 16);
        unsigned int hi = (unsigned int)f2bf(xv0[2]) | ((unsigned int)f2bf(xv0[3]) << 16);
        *((uint2*)&xCur[row * 40 + sub * 4]) = make_uint2(lo, hi);
    }

    f32x4 acc[4][4] = {};
    for (int kb = 0; kb < 31; ++kb) {
        // stage A(kb+1) into aNxt
        const unsigned short* asrc = A_P + (size_t)(kb + 1) * 16384 + tid * 8;
#pragma unroll
        for (int i = 0; i < 4; ++i)
            load16_lds(&aNxt[tid * 8 + i * 4096], asrc + i * 4096);
        SCHED_FENCE();
        // prefetch X(kb+2) (clamped; dup load at kb=30 is harmless)
        int kbn = (kb + 2 <= 31) ? kb + 2 : 31;
        f32x4 xv_new = *(const f32x4*)(xp + (size_t)kbn * 32);
        // write x(kb+1) from xv_hold; implicit vmcnt wait on xv_hold drains
        // everything older, incl. GLL A(kb) -> aCur is ready for compute
        unsigned int lo = (unsigned int)f2bf(xv_hold[0]) | ((unsigned int)f2bf(xv_hold[1]) << 16);
        unsigned int hi = (unsigned int)f2bf(xv_hold[2]) | ((unsigned int)f2bf(xv_hold[3]) << 16);
        *((uint2*)&xNxt[row * 40 + sub * 4]) = make_uint2(lo, hi);
        WAIT_LGKM0();
        SCHED_FENCE();
        BAR();
        SCHED_FENCE();
        // compute tile kb from aCur/xCur
        bf16x8 af[4], bv[4];
#pragma unroll
        for (int m = 0; m < 4; ++m)
            af[m] = *(const bf16x8*)&xCur[(m * 16 + (lane & 15)) * 40 + (lane >> 4) * 8];
#pragma unroll
        for (int n = 0; n < 4; ++n)
            bv[n] = *(const bf16x8*)&aCur[(w * 4 + n) * 512 + lane * 8];
#pragma unroll
        for (int m = 0; m < 4; ++m)
#pragma unroll
            for (int n = 0; n < 4; ++n)
                acc[m][n] = MFMA_16x16x32(af[m], bv[n], acc[m][n]);
        BAR();
        // swap buffers / rotate prefetch
        unsigned short* t;
        t = aCur; aCur = aNxt; aNxt = t;
        t = xCur; xCur = xNxt; xNxt = t;
        xv_hold = xv_new;
    }
    // peeled kb=31: GLL A(31) was issued last iter, not yet drained
    WAIT_VM0_LGKM0();
    SCHED_FENCE();
    BAR();
    SCHED_FENCE();
    {
        bf16x8 af[4], bv[4];
#pragma unroll
        for (int m = 0; m < 4; ++m)
            af[m] = *(const bf16x8*)&xCur[(m * 16 + (lane & 15)) * 40 + (lane >> 4) * 8];
#pragma unroll
        for (int n = 0; n < 4; ++n)
            bv[n] = *(const bf16x8*)&aCur[(w * 4 + n) * 512 + lane * 8];
#pragma unroll
        for (int m = 0; m < 4; ++m)
#pragma unroll
            for (int n = 0; n < 4; ++n)
                acc[m][n] = MFMA_16x16x32(af[m], bv[n], acc[m][n]);
    }
    __syncthreads();   // full drain before hb (unions with a/x buffers)

    // epilogue: scale by weight, bf16, bounce through LDS to A-frag packing
#pragma unroll
    for (int m = 0; m < 4; ++m) {
        float wv[4];
#pragma unroll
        for (int r = 0; r < 4; ++r)
            wv[r] = wl[(m * 16 + (lane >> 4) * 4 + r) * 8 + w];
#pragma unroll
        for (int n = 0; n < 4; ++n) {
            int col = w * 64 + n * 16 + (lane & 15);
#pragma unroll
            for (int r = 0; r < 4; ++r) {
                int rr = m * 16 + (lane >> 4) * 4 + r;
                sm.hb[rr * 520 + col] = f2bf(acc[m][n][r] * wv[r]);
            }
        }
    }
    __syncthreads();
    // H_P: [N/16][ER/32=16][lane 64][j 8]
#pragma unroll
    for (int it = 0; it < 8; ++it) {
        int gi = tid + it * 512;
        int ft = gi >> 6;                 // fragtile 0..63
        int l2 = gi & 63;
        int rowblk = ft >> 4;             // 0..3
        int kblk = ft & 15;               // 0..15
        int rr = rowblk * 16 + (l2 & 15);
        int cs = kblk * 32 + (l2 >> 4) * 8;
        uint4 v = *(const uint4*)&sm.hb[rr * 520 + cs];
        *(uint4*)&H_P[(((size_t)blk * 4 + rowblk) * 16 + kblk) * 512 + l2 * 8] = v;
    }
}

// ---------------------------------------------------------------------------
// Stage 2 (R4-validated): out[N,1024] = H @ B_cat, fp32 out. Tile 128x256,
// 8 waves (2x4), K=512, double-buffered with counted vmcnt(3).
// ---------------------------------------------------------------------------
__global__ __launch_bounds__(512, 4) void stage2_kernel(
        const unsigned short* __restrict__ H_P, const unsigned short* __restrict__ B_P,
        float* __restrict__ Out) {
    __shared__ unsigned short a_lds[2][8 * 512];    // 2 x 8KB
    __shared__ unsigned short b_lds[2][16 * 512];   // 2 x 16KB

    int tid = threadIdx.x;
    int lane = tid & 63;
    int wid = tid >> 6;
    int wr = wid >> 2, wc = wid & 3;
    int bw = blockIdx.x;                          // 2048 blocks
    int mt = ((bw >> 5) << 3) | (bw & 7);         // 0..511  (XCD = mt & 7)
    int nt = (bw >> 3) & 3;                       // 0..3

    unsigned short* aCur = a_lds[0];
    unsigned short* aNxt = a_lds[1];
    unsigned short* bCur = b_lds[0];
    unsigned short* bNxt = b_lds[1];

    const unsigned short* hbase = H_P + ((size_t)mt * 8 + wid) * 16 * 512 + lane * 8;
    const unsigned short* bbase = B_P + (size_t)nt * 16 * 512 + tid * 8;

    load16_lds(&aCur[tid * 8], hbase);
    load16_lds(&bCur[tid * 8], bbase);
    load16_lds(&bCur[tid * 8 + 4096], bbase + 4096);

    f32x4 acc[4][4] = {};
    for (int kc = 0; kc < 15; ++kc) {
        load16_lds(&aNxt[tid * 8], hbase + (size_t)(kc + 1) * 512);
        load16_lds(&bNxt[tid * 8], bbase + (size_t)(kc + 1) * 32768);
        load16_lds(&bNxt[tid * 8 + 4096], bbase + (size_t)(kc + 1) * 32768 + 4096);
        WAIT_VM3();
        SCHED_FENCE();
        BAR();
        SCHED_FENCE();
        bf16x8 af[4], bv[4];
#pragma unroll
        for (int m = 0; m < 4; ++m)
            af[m] = *(const bf16x8*)&aCur[(wr * 4 + m) * 512 + lane * 8];
#pragma unroll
        for (int n = 0; n < 4; ++n)
            bv[n] = *(const bf16x8*)&bCur[(wc * 4 + n) * 512 + lane * 8];
#pragma unroll
        for (int m = 0; m < 4; ++m)
#pragma unroll
            for (int n = 0; n < 4; ++n)
                acc[m][n] = MFMA_16x16x32(af[m], bv[n], acc[m][n]);
        BAR();
        unsigned short* t;
        t = aCur; aCur = aNxt; aNxt = t;
        t = bCur; bCur = bNxt; bNxt = t;
    }
    WAIT_VM0();
    SCHED_FENCE();
    BAR();
    SCHED_FENCE();
    {
        bf16x8 af[4], bv[4];
#pragma unroll
        for (int m = 0; m < 4; ++m)
            af[m] = *(const bf16x8*)&aCur[(wr * 4 + m) * 512 + lane * 8];
#pragma unroll
        for (int n = 0; n < 4; ++n)
            bv[n] = *(const bf16x8*)&bCur[(wc * 4 + n) * 512 + lane * 8];
#pragma unroll
        for (int m = 0; m < 4; ++m)
#pragma unroll
            for (int n = 0; n < 4; ++n)
                acc[m][n] = MFMA_16x16x32(af[m], bv[n], acc[m][n]);
    }

    size_t rb = (size_t)mt * 128 + wr * 64;
    int cb = nt * 256 + wc * 64;
#pragma unroll
    for (int m = 0; m < 4; ++m)
#pragma unroll
        for (int n = 0; n < 4; ++n) {
            int col = cb + n * 16 + (lane & 15);
#pragma unroll
            for (int r = 0; r < 4; ++r) {
                size_t rrow = rb + m * 16 + (lane >> 4) * 4 + r;
                Out[rrow * 1024 + col] = acc[m][n][r];
            }
        }
}

// ---------------------------------------------------------------------------
extern "C" void kernel_launch(void* const* d_in, const int* in_sizes, int n_in,
                              void* d_out, int out_size, void* d_ws, size_t ws_size,
                              hipStream_t stream) {
    const float* X  = (const float*)d_in[0];   // [65536][1024]
    const float* GW = (const float*)d_in[1];   // [1024][8]
    const float* GB = (const float*)d_in[2];   // [8]
    const float* LA = (const float*)d_in[3];   // [8][1024][64]
    const float* LB = (const float*)d_in[4];   // [8][64][1024]
    float* Out = (float*)d_out;                // [65536][1024]

    char* ws = (char*)d_ws;
    float*          Wg  = (float*)ws;                              // 2MB  [N][8]
    unsigned short* A_P = (unsigned short*)(ws + (2u << 20));      // 1MB  packed lora_A
    unsigned short* B_P = (unsigned short*)(ws + (3u << 20));      // 1MB  packed lora_B
    unsigned short* H_P = (unsigned short*)(ws + (4u << 20));      // 64MB packed H

    convert_pack<<<4096, 256, 0, stream>>>(LA, LB, A_P, B_P);
    gate_kernel<<<4096, 256, 0, stream>>>(X, GW, GB, Wg);
    stage1_kernel<<<1024, 512, 0, stream>>>(X, A_P, Wg, H_P);
    stage2_kernel<<<2048, 512, 0, stream>>>(H_P, B_P, Out);
}